// Round 13
// baseline (105.146 us; speedup 1.0000x reference)
//
#include <hip/hip_runtime.h>
#include <hip/hip_bf16.h>
#include <math.h>

// Problem constants
#define BATCH   4096
#define DIM     512
#define DIMB    256                         // bytes per fp4 row
#define TWO_B   8192
#define INV_T   10.0f                       // 1/TEMP
#define LSE_SCALE 14.426950408889634f       // log2(e)/TEMP
#define NTRI    2080                        // 64*65/2 upper-triangle tiles

typedef __attribute__((ext_vector_type(8)))  int   intx8;
typedef __attribute__((ext_vector_type(4)))  int   intx4;
typedef __attribute__((ext_vector_type(16))) float floatx16; // 32x32 MFMA acc

// E8M0 scale byte: 2^(x-127). 122 -> 2^-5 per operand (z stored x32).
#define SCALE_E8M0 122
#define FMT_FP4 4                           // cbsz/blgp encoding for fp4 e2m1

// LESSON (rounds 10/11): __threadfence() per block on gfx950 = per-XCD L2
// writeback (non-coherent L2s) ~= +110 us across 2080 blocks. Device-scope
// atomics alone are cheap (they execute at the coherence point); ordering
// before the completion-counter bump needs only the vmcnt(0) drain that
// __syncthreads() already performs. NO FENCE.

// e2m1 encode of |v|<=~6 with round-to-nearest. Values: 0,.5,1,1.5,2,3,4,6.
static __device__ inline unsigned fp4_enc(float v) {
    const unsigned s = (__float_as_uint(v) >> 28) & 8u;   // sign -> bit3
    const float a = fabsf(v);
    unsigned c;
    if      (a < 0.25f) c = 0;
    else if (a < 0.75f) c = 1;
    else if (a < 1.25f) c = 2;
    else if (a < 1.75f) c = 3;
    else if (a < 2.5f)  c = 4;
    else if (a < 3.5f)  c = 5;
    else if (a < 5.0f)  c = 6;
    else                c = 7;
    return s | c;
}

// Fragment-order z4 layout: for global row R and row-byte t (elements
// 2t,2t+1) the byte lives at
//   (R>>5)*8192 + (t>>5)*1024 + ((t>>4)&1)*512 + (R&31)*16 + (t&15)
// so an MFMA A/B fragment load (row-block rb, slab s, lane = r + 32*c) is
// ONE contiguous 1 KB segment: rb*8192 + s*1024 + c*512 + r*16.
static __device__ inline size_t z4t_addr(int R, int t) {
    return (size_t)(R >> 5) * 8192 + (size_t)(t >> 5) * 1024 +
           (size_t)((t >> 4) & 1) * 512 + (size_t)(R & 31) * 16 + (t & 15);
}

// ---------------------------------------------------------------------------
// Kernel 1: L2-normalize pairs; write z4t = fp4_e2m1(32 * z) in fragment
// order, and fp32 pos[i] = cos(z_i, z_{i+B})/TEMP. Thread t owns elements
// 2t,2t+1 (= row-byte t). Blocks 0..31 zero sumexp[8192]; block 32 zeroes
// the completion counter (norm completes before sim: stream order + the
// end-of-kernel cache release makes plain-store init visible to sim's
// device-scope atomics).
// ---------------------------------------------------------------------------
__global__ __launch_bounds__(256) void norm_kernel(
    const float* __restrict__ p1, const float* __restrict__ p2,
    unsigned char* __restrict__ z4, float* __restrict__ pos,
    float* __restrict__ sumexp, unsigned* __restrict__ counter)
{
    const int i = blockIdx.x;          // 0..4095
    const int t = threadIdx.x;         // 0..255
    const int wave = t >> 6, lane = t & 63;

    if (i < 32) sumexp[i * 256 + t] = 0.0f;
    if (i == 32 && t == 0) *counter = 0u;

    const float2 xv = ((const float2*)(p1 + (size_t)i * DIM))[t];
    const float2 yv = ((const float2*)(p2 + (size_t)i * DIM))[t];

    float sx = fmaf(xv.x, xv.x, xv.y * xv.y);
    float sy = fmaf(yv.x, yv.x, yv.y * yv.y);
    float sd = fmaf(xv.x, yv.x, xv.y * yv.y);

    #pragma unroll
    for (int off = 32; off > 0; off >>= 1) {
        sx += __shfl_down(sx, off);
        sy += __shfl_down(sy, off);
        sd += __shfl_down(sd, off);
    }

    __shared__ float red[3][4];
    if (lane == 0) { red[0][wave] = sx; red[1][wave] = sy; red[2][wave] = sd; }
    __syncthreads();
    sx = red[0][0] + red[0][1] + red[0][2] + red[0][3];
    sy = red[1][0] + red[1][1] + red[1][2] + red[1][3];
    sd = red[2][0] + red[2][1] + red[2][2] + red[2][3];

    const float rx = 1.0f / fmaxf(sqrtf(sx), 1e-12f);
    const float ry = 1.0f / fmaxf(sqrtf(sy), 1e-12f);
    const float gx = 32.0f * rx, gy = 32.0f * ry;   // x32 -> sigma ~1.4 in fp4

    z4[z4t_addr(i, t)] =
        (unsigned char)(fp4_enc(xv.x * gx) | (fp4_enc(xv.y * gx) << 4));
    z4[z4t_addr(i + BATCH, t)] =
        (unsigned char)(fp4_enc(yv.x * gy) | (fp4_enc(yv.y * gy) << 4));

    if (t == 0) pos[i] = sd * rx * ry * INV_T;
}

// ---------------------------------------------------------------------------
// Kernel 2: UPPER-TRIANGLE fused z@z^T tiles in MX-FP4, LDS-free K-loop,
// fused LSE tail via completion counter — NO FENCE (see lesson above).
//   - colsum/rowsum accumulate into sumexp[8192] via unsafeAtomicAdd
//     (HW device-scope f32 add at the coherence point).
//   - __syncthreads() drains every thread's outstanding atomics (vmcnt(0))
//     before thread 0 bumps the counter.
//   - the block observing old == NTRI-1 computes
//     out = mean(log(sumexp) - pos) with agent-scope atomic loads.
// ---------------------------------------------------------------------------
__global__ __launch_bounds__(256, 4) void sim_kernel(
    const unsigned char* __restrict__ z4, const float* __restrict__ pos,
    float* __restrict__ sumexp, unsigned* __restrict__ counter,
    float* __restrict__ out)
{
    __shared__ __align__(16) unsigned char smem[19968];
    float* rowbuf = (float*)smem;               // [64][68] f32
    float* colred = (float*)(smem + 17408);     // [128*5] f32

    // --- triangular decode: blockIdx.x -> (rt, ct), rt <= ct --------------
    const int idx = blockIdx.x;
    int rt = (int)((129.0 - sqrt(16641.0 - 8.0 * (double)idx)) * 0.5);
    while (64 * (rt + 1) - ((rt + 1) * rt) / 2 <= idx) ++rt;
    while (64 * rt - (rt * (rt - 1)) / 2 > idx) --rt;
    const int ct = rt + (idx - (64 * rt - (rt * (rt - 1)) / 2));
    const bool diag = (rt == ct);

    const int t = threadIdx.x;
    const int wave = t >> 6, lane = t & 63;
    const int wr = wave >> 1, wc = wave & 1;   // 2x2 wave grid, 64x64 each
    const int lrow  = lane & 31;               // m/n within a 32-tile
    const int lhalf = lane >> 5;               // k-half (chunk) selector

    // Per-lane byte offset within a (row-block, slab) 1 KB segment.
    const int loff = lhalf * 512 + lrow * 16;
    const unsigned char* Abase = z4 + (size_t)(rt * 4 + wr * 2) * 8192 + loff;
    const unsigned char* Bbase = z4 + (size_t)(ct * 4 + wc * 2) * 8192 + loff;

    floatx16 acc[2][2];
    #pragma unroll
    for (int mi = 0; mi < 2; ++mi)
        #pragma unroll
        for (int ni = 0; ni < 2; ++ni)
            acc[mi][ni] = (floatx16)0.0f;

    // --- barrier-free K-loop: 8 slabs x 4 frag gathers x 4 MFMA -----------
    #pragma unroll
    for (int s = 0; s < 8; ++s) {
        intx8 af[2], bf[2];
        #pragma unroll
        for (int mi = 0; mi < 2; ++mi) {
            const intx4 a0 = *(const intx4*)(Abase + mi * 8192 + s * 1024);
            const intx4 b0 = *(const intx4*)(Bbase + mi * 8192 + s * 1024);
            #pragma unroll
            for (int j = 0; j < 4; ++j) {
                af[mi][j] = a0[j]; af[mi][j + 4] = 0;
                bf[mi][j] = b0[j]; bf[mi][j + 4] = 0;
            }
        }
        #pragma unroll
        for (int mi = 0; mi < 2; ++mi)
            #pragma unroll
            for (int ni = 0; ni < 2; ++ni)
                acc[mi][ni] = __builtin_amdgcn_mfma_scale_f32_32x32x64_f8f6f4(
                    af[mi], bf[ni], acc[mi][ni],
                    FMT_FP4, FMT_FP4,           // cbsz, blgp = fp4 e2m1
                    0, SCALE_E8M0,              // opsel_a, scale_a (2^-5)
                    0, SCALE_E8M0);             // opsel_b, scale_b (2^-5)
    }

    // --- epilogue ----------------------------------------------------------
    // C/D layout (shape-determined, m74/m101/m121-128): col = lane&31,
    // row = (reg&3) + 8*(reg>>2) + 4*(lane>>5), within each 32x32 tile.
    float cs[2] = {0.0f, 0.0f};     // per-column sums (2 cols this lane owns)
    float rw[2][16];                // per-row partials (summed over ni in-lane)
    #pragma unroll
    for (int mi = 0; mi < 2; ++mi)
        #pragma unroll
        for (int r = 0; r < 16; ++r)
            rw[mi][r] = 0.0f;

    #pragma unroll
    for (int mi = 0; mi < 2; ++mi) {
        #pragma unroll
        for (int ni = 0; ni < 2; ++ni) {
            const int col_l = wc * 64 + ni * 32 + lrow;
            #pragma unroll
            for (int r = 0; r < 16; ++r) {
                const int row_l = wr * 64 + mi * 32 + lhalf * 4 + (r & 3) + 8 * (r >> 2);
                float ee = __builtin_amdgcn_exp2f(acc[mi][ni][r] * LSE_SCALE);
                if (diag && (row_l == col_l)) ee = 0.0f;   // -inf self mask
                cs[ni] += ee;
                rw[mi][r] += ee;
            }
        }
    }

    // col sums -> colred (4 partials/column, stride-5); rowbuf phase-0 now.
    const int slot = wr * 2 + lhalf;
    #pragma unroll
    for (int ni = 0; ni < 2; ++ni)
        colred[(wc * 64 + ni * 32 + lrow) * 5 + slot] = cs[ni];
    if (!diag && wr == 0) {
        #pragma unroll
        for (int mi = 0; mi < 2; ++mi)
            #pragma unroll
            for (int r = 0; r < 16; ++r) {
                const int lr = mi * 32 + lhalf * 4 + (r & 3) + 8 * (r >> 2);
                rowbuf[lr * 68 + wc * 32 + lrow] = rw[mi][r];
            }
    }
    __syncthreads();

    if (t < 128) {
        const float s = colred[t * 5 + 0] + colred[t * 5 + 1] +
                        colred[t * 5 + 2] + colred[t * 5 + 3];
        unsafeAtomicAdd(&sumexp[ct * 128 + t], s);  // HW f32 device atomic
    }

    if (!diag) {
        // phase-0 read (tile rows 0..63)
        if (t < 128) {
            const int r = t >> 1, h = t & 1;
            const float4* rb = (const float4*)(rowbuf + r * 68 + h * 32);
            float s = 0.0f;
            #pragma unroll
            for (int j = 0; j < 8; ++j) {
                const float4 v = rb[j];
                s += (v.x + v.y) + (v.z + v.w);
            }
            s += __shfl_xor(s, 1, 64);
            if (h == 0) unsafeAtomicAdd(&sumexp[rt * 128 + r], s);
        }
        __syncthreads();
        if (wr == 1) {                 // phase-1 write (tile rows 64..127)
            #pragma unroll
            for (int mi = 0; mi < 2; ++mi)
                #pragma unroll
                for (int r = 0; r < 16; ++r) {
                    const int lr = mi * 32 + lhalf * 4 + (r & 3) + 8 * (r >> 2);
                    rowbuf[lr * 68 + wc * 32 + lrow] = rw[mi][r];
                }
        }
        __syncthreads();
        if (t < 128) {
            const int r = t >> 1, h = t & 1;
            const float4* rb = (const float4*)(rowbuf + r * 68 + h * 32);
            float s = 0.0f;
            #pragma unroll
            for (int j = 0; j < 8; ++j) {
                const float4 v = rb[j];
                s += (v.x + v.y) + (v.z + v.w);
            }
            s += __shfl_xor(s, 1, 64);
            if (h == 0) unsafeAtomicAdd(&sumexp[rt * 128 + 64 + r], s);
        }
    }

    // --- completion-counter fused LSE tail (NO fence) ----------------------
    __syncthreads();   // implicit s_waitcnt vmcnt(0): all this block's atomics
                       // have completed at the coherence point
    __shared__ unsigned lastflag;
    if (t == 0) lastflag = (atomicAdd(counter, 1u) == NTRI - 1) ? 1u : 0u;
    __syncthreads();
    if (lastflag) {
        float lsum = 0.0f;
        #pragma unroll
        for (int j = 0; j < 32; ++j) {
            const int row = j * 256 + t;
            const float s = __hip_atomic_load(&sumexp[row], __ATOMIC_RELAXED,
                                              __HIP_MEMORY_SCOPE_AGENT);
            lsum += __logf(s) - pos[row & (BATCH - 1)];
        }
        #pragma unroll
        for (int off = 32; off > 0; off >>= 1)
            lsum += __shfl_down(lsum, off);
        float* wsum = (float*)smem;
        if ((t & 63) == 0) wsum[t >> 6] = lsum;
        __syncthreads();
        if (t == 0)
            out[0] = (wsum[0] + wsum[1] + wsum[2] + wsum[3]) *
                     (1.0f / (float)TWO_B);
    }
}

// ---------------------------------------------------------------------------
extern "C" void kernel_launch(void* const* d_in, const int* in_sizes, int n_in,
                              void* d_out, int out_size, void* d_ws, size_t ws_size,
                              hipStream_t stream)
{
    const float* p1 = (const float*)d_in[0];
    const float* p2 = (const float*)d_in[1];
    float* out = (float*)d_out;

    // Workspace layout (all fully rewritten every call; poison-safe):
    //   z4t      : 8192*256 fp4 (fragment-ordered) = 2,097,152 B
    //   pos      : 4096 f32                        =    16,384 B
    //   sumexp   : 8192 f32                        =    32,768 B
    //   counter  : 1 u32                           =       128 B
    char* ws = (char*)d_ws;
    unsigned char* z4  = (unsigned char*)ws;
    float* pos         = (float*)(ws + 2097152);
    float* sumexp      = (float*)(ws + 2097152 + 16384);
    unsigned* counter  = (unsigned*)(ws + 2097152 + 16384 + 32768);

    norm_kernel<<<BATCH, 256, 0, stream>>>(p1, p2, z4, pos, sumexp, counter);
    sim_kernel<<<NTRI, 256, 0, stream>>>(z4, pos, sumexp, counter, out);
}

// Round 14
// 90.218 us; speedup vs baseline: 1.1655x; 1.1655x over previous
//
#include <hip/hip_runtime.h>
#include <hip/hip_bf16.h>
#include <math.h>

// Problem constants
#define BATCH   4096
#define DIM     512
#define DIMB    256                         // bytes per fp4 row
#define TWO_B   8192
#define INV_T   10.0f                       // 1/TEMP
#define LSE_SCALE 14.426950408889634f       // log2(e)/TEMP
#define NTRI    2080                        // 64*65/2 upper-triangle tiles

typedef __attribute__((ext_vector_type(8)))  int   intx8;
typedef __attribute__((ext_vector_type(4)))  int   intx4;
typedef __attribute__((ext_vector_type(16))) float floatx16; // 32x32 MFMA acc

// E8M0 scale byte: 2^(x-127). 122 -> 2^-5 per operand (z stored x32; 2^-10
// total undoes 32*32).
#define SCALE_E8M0 122
#define FMT_FP4 4                           // cbsz/blgp encoding for fp4 e2m1

// SESSION LESSONS (measured, rounds 10-13):
//  - __threadfence() per block on gfx950 => per-XCD L2 writeback
//    (non-coherent L2s): ~+97 us over 2080 blocks. Never fuse reductions
//    via per-block device fences on CDNA4.
//  - Even fence-free, 266k device-scope f32 atomics + completion counter
//    cost ~+14 us vs plain stores + a 2 us reduction kernel. The 3-kernel
//    split wins.
//  - (256,4) vs (256,3) launch bounds: no measurable difference; keep 3.
//  - LDS staging in the K-loop (any barrier count) loses to direct
//    fragment-ordered global gathers from L2 for this 2 MB operand.

// e2m1 encode of |v|<=~6 with round-to-nearest. Values: 0,.5,1,1.5,2,3,4,6.
static __device__ inline unsigned fp4_enc(float v) {
    const unsigned s = (__float_as_uint(v) >> 28) & 8u;   // sign -> bit3
    const float a = fabsf(v);
    unsigned c;
    if      (a < 0.25f) c = 0;
    else if (a < 0.75f) c = 1;
    else if (a < 1.25f) c = 2;
    else if (a < 1.75f) c = 3;
    else if (a < 2.5f)  c = 4;
    else if (a < 3.5f)  c = 5;
    else if (a < 5.0f)  c = 6;
    else                c = 7;
    return s | c;
}

// Fragment-order z4 layout: for global row R and row-byte t (elements
// 2t,2t+1) the byte lives at
//   (R>>5)*8192 + (t>>5)*1024 + ((t>>4)&1)*512 + (R&31)*16 + (t&15)
// so an MFMA A/B fragment load (row-block rb, slab s, lane = r + 32*c) is
// ONE contiguous 1 KB segment: rb*8192 + s*1024 + c*512 + r*16.
static __device__ inline size_t z4t_addr(int R, int t) {
    return (size_t)(R >> 5) * 8192 + (size_t)(t >> 5) * 1024 +
           (size_t)((t >> 4) & 1) * 512 + (size_t)(R & 31) * 16 + (t & 15);
}

// ---------------------------------------------------------------------------
// Kernel 1: L2-normalize pairs; write z4t = fp4_e2m1(32 * z) in fragment
// order, and fp32 pos[i] = cos(z_i, z_{i+B})/TEMP. Thread t owns elements
// 2t,2t+1 (= row-byte t). Also zeroes out[0] (stream-ordered before lse).
// ---------------------------------------------------------------------------
__global__ __launch_bounds__(256) void norm_kernel(
    const float* __restrict__ p1, const float* __restrict__ p2,
    unsigned char* __restrict__ z4, float* __restrict__ pos,
    float* __restrict__ out)
{
    const int i = blockIdx.x;          // 0..4095
    const int t = threadIdx.x;         // 0..255
    const int wave = t >> 6, lane = t & 63;

    if (i == 0 && t == 0) out[0] = 0.0f;   // atomic accumulator init

    const float2 xv = ((const float2*)(p1 + (size_t)i * DIM))[t];
    const float2 yv = ((const float2*)(p2 + (size_t)i * DIM))[t];

    float sx = fmaf(xv.x, xv.x, xv.y * xv.y);
    float sy = fmaf(yv.x, yv.x, yv.y * yv.y);
    float sd = fmaf(xv.x, yv.x, xv.y * yv.y);

    #pragma unroll
    for (int off = 32; off > 0; off >>= 1) {
        sx += __shfl_down(sx, off);
        sy += __shfl_down(sy, off);
        sd += __shfl_down(sd, off);
    }

    __shared__ float red[3][4];
    if (lane == 0) { red[0][wave] = sx; red[1][wave] = sy; red[2][wave] = sd; }
    __syncthreads();
    sx = red[0][0] + red[0][1] + red[0][2] + red[0][3];
    sy = red[1][0] + red[1][1] + red[1][2] + red[1][3];
    sd = red[2][0] + red[2][1] + red[2][2] + red[2][3];

    const float rx = 1.0f / fmaxf(sqrtf(sx), 1e-12f);
    const float ry = 1.0f / fmaxf(sqrtf(sy), 1e-12f);
    const float gx = 32.0f * rx, gy = 32.0f * ry;   // x32 -> sigma ~1.4 in fp4

    z4[z4t_addr(i, t)] =
        (unsigned char)(fp4_enc(xv.x * gx) | (fp4_enc(xv.y * gx) << 4));
    z4[z4t_addr(i + BATCH, t)] =
        (unsigned char)(fp4_enc(yv.x * gy) | (fp4_enc(yv.y * gy) << 4));

    if (t == 0) pos[i] = sd * rx * ry * INV_T;
}

// ---------------------------------------------------------------------------
// Kernel 2: UPPER-TRIANGLE fused z@z^T tiles in MX-FP4, LDS-FREE K-loop.
// Fragments gathered directly from fragment-ordered z4t (one coalesced 1 KB
// global_load_dwordx4 per wave per fragment) — no LDS staging, no barriers
// in the K-loop. z4t is 2 MB -> L2-resident per XCD.
// Epilogue: exp2 + diag mask; colsum in-lane; rowsum via 2-phase LDS
// transpose; plain stores to partial[rt][ct*128+j] / partial[ct][rt*128+i]
// (every slot written exactly once -> deterministic, no atomics).
// ---------------------------------------------------------------------------
__global__ __launch_bounds__(256, 3) void sim_kernel(
    const unsigned char* __restrict__ z4, float* __restrict__ partial)
{
    __shared__ __align__(16) unsigned char smem[19968];
    float* rowbuf = (float*)smem;               // [64][68] f32
    float* colred = (float*)(smem + 17408);     // [128*5] f32

    // --- triangular decode: blockIdx.x -> (rt, ct), rt <= ct --------------
    const int idx = blockIdx.x;
    int rt = (int)((129.0 - sqrt(16641.0 - 8.0 * (double)idx)) * 0.5);
    while (64 * (rt + 1) - ((rt + 1) * rt) / 2 <= idx) ++rt;
    while (64 * rt - (rt * (rt - 1)) / 2 > idx) --rt;
    const int ct = rt + (idx - (64 * rt - (rt * (rt - 1)) / 2));
    const bool diag = (rt == ct);

    const int t = threadIdx.x;
    const int wave = t >> 6, lane = t & 63;
    const int wr = wave >> 1, wc = wave & 1;   // 2x2 wave grid, 64x64 each
    const int lrow  = lane & 31;               // m/n within a 32-tile
    const int lhalf = lane >> 5;               // k-half (chunk) selector

    // Per-lane byte offset within a (row-block, slab) 1 KB segment.
    const int loff = lhalf * 512 + lrow * 16;
    const unsigned char* Abase = z4 + (size_t)(rt * 4 + wr * 2) * 8192 + loff;
    const unsigned char* Bbase = z4 + (size_t)(ct * 4 + wc * 2) * 8192 + loff;

    floatx16 acc[2][2];
    #pragma unroll
    for (int mi = 0; mi < 2; ++mi)
        #pragma unroll
        for (int ni = 0; ni < 2; ++ni)
            acc[mi][ni] = (floatx16)0.0f;

    // --- barrier-free K-loop: 8 slabs x 4 frag gathers x 4 MFMA -----------
    #pragma unroll
    for (int s = 0; s < 8; ++s) {
        intx8 af[2], bf[2];
        #pragma unroll
        for (int mi = 0; mi < 2; ++mi) {
            const intx4 a0 = *(const intx4*)(Abase + mi * 8192 + s * 1024);
            const intx4 b0 = *(const intx4*)(Bbase + mi * 8192 + s * 1024);
            #pragma unroll
            for (int j = 0; j < 4; ++j) {
                af[mi][j] = a0[j]; af[mi][j + 4] = 0;
                bf[mi][j] = b0[j]; bf[mi][j + 4] = 0;
            }
        }
        #pragma unroll
        for (int mi = 0; mi < 2; ++mi)
            #pragma unroll
            for (int ni = 0; ni < 2; ++ni)
                acc[mi][ni] = __builtin_amdgcn_mfma_scale_f32_32x32x64_f8f6f4(
                    af[mi], bf[ni], acc[mi][ni],
                    FMT_FP4, FMT_FP4,           // cbsz, blgp = fp4 e2m1
                    0, SCALE_E8M0,              // opsel_a, scale_a (2^-5)
                    0, SCALE_E8M0);             // opsel_b, scale_b (2^-5)
    }

    // --- epilogue ----------------------------------------------------------
    // C/D layout (shape-determined, m74/m101/m121-128): col = lane&31,
    // row = (reg&3) + 8*(reg>>2) + 4*(lane>>5), within each 32x32 tile.
    float cs[2] = {0.0f, 0.0f};     // per-column sums (2 cols this lane owns)
    float rw[2][16];                // per-row partials (summed over ni in-lane)
    #pragma unroll
    for (int mi = 0; mi < 2; ++mi)
        #pragma unroll
        for (int r = 0; r < 16; ++r)
            rw[mi][r] = 0.0f;

    #pragma unroll
    for (int mi = 0; mi < 2; ++mi) {
        #pragma unroll
        for (int ni = 0; ni < 2; ++ni) {
            const int col_l = wc * 64 + ni * 32 + lrow;
            #pragma unroll
            for (int r = 0; r < 16; ++r) {
                const int row_l = wr * 64 + mi * 32 + lhalf * 4 + (r & 3) + 8 * (r >> 2);
                float ee = __builtin_amdgcn_exp2f(acc[mi][ni][r] * LSE_SCALE);
                if (diag && (row_l == col_l)) ee = 0.0f;   // -inf self mask
                cs[ni] += ee;
                rw[mi][r] += ee;
            }
        }
    }

    // col sums -> colred (4 partials/column, stride-5); rowbuf phase-0 now.
    const int slot = wr * 2 + lhalf;
    #pragma unroll
    for (int ni = 0; ni < 2; ++ni)
        colred[(wc * 64 + ni * 32 + lrow) * 5 + slot] = cs[ni];
    if (!diag && wr == 0) {
        #pragma unroll
        for (int mi = 0; mi < 2; ++mi)
            #pragma unroll
            for (int r = 0; r < 16; ++r) {
                const int lr = mi * 32 + lhalf * 4 + (r & 3) + 8 * (r >> 2);
                rowbuf[lr * 68 + wc * 32 + lrow] = rw[mi][r];
            }
    }
    __syncthreads();

    if (t < 128) {
        const float s = colred[t * 5 + 0] + colred[t * 5 + 1] +
                        colred[t * 5 + 2] + colred[t * 5 + 3];
        partial[(size_t)rt * TWO_B + (size_t)ct * 128 + t] = s;
    }

    if (!diag) {
        // phase-0 read (tile rows 0..63)
        if (t < 128) {
            const int r = t >> 1, h = t & 1;
            const float4* rb = (const float4*)(rowbuf + r * 68 + h * 32);
            float s = 0.0f;
            #pragma unroll
            for (int j = 0; j < 8; ++j) {
                const float4 v = rb[j];
                s += (v.x + v.y) + (v.z + v.w);
            }
            s += __shfl_xor(s, 1, 64);
            if (h == 0)
                partial[(size_t)ct * TWO_B + (size_t)rt * 128 + r] = s;
        }
        __syncthreads();
        if (wr == 1) {                 // phase-1 write (tile rows 64..127)
            #pragma unroll
            for (int mi = 0; mi < 2; ++mi)
                #pragma unroll
                for (int r = 0; r < 16; ++r) {
                    const int lr = mi * 32 + lhalf * 4 + (r & 3) + 8 * (r >> 2);
                    rowbuf[lr * 68 + wc * 32 + lrow] = rw[mi][r];
                }
        }
        __syncthreads();
        if (t < 128) {
            const int r = t >> 1, h = t & 1;
            const float4* rb = (const float4*)(rowbuf + r * 68 + h * 32);
            float s = 0.0f;
            #pragma unroll
            for (int j = 0; j < 8; ++j) {
                const float4 v = rb[j];
                s += (v.x + v.y) + (v.z + v.w);
            }
            s += __shfl_xor(s, 1, 64);
            if (h == 0)
                partial[(size_t)ct * TWO_B + (size_t)rt * 128 + 64 + r] = s;
        }
    }
}

// ---------------------------------------------------------------------------
// Kernel 3: per-row sumexp over 64 tile contributions -> lse - pos term,
// block-reduced, atomically accumulated into out.
// ---------------------------------------------------------------------------
__global__ __launch_bounds__(256) void lse_kernel(
    const float* __restrict__ partial, const float* __restrict__ pos,
    float* __restrict__ out)
{
    const int t = threadIdx.x;
    const int row = blockIdx.x * 256 + t;
    float s = 0.0f;
    #pragma unroll 8
    for (int tile = 0; tile < 64; ++tile)
        s += partial[(size_t)tile * TWO_B + row];
    float term = logf(s) - pos[row & (BATCH - 1)];   // sim_ij == sim_ji

    #pragma unroll
    for (int off = 32; off > 0; off >>= 1)
        term += __shfl_down(term, off);
    __shared__ float wsum[4];
    if ((t & 63) == 0) wsum[t >> 6] = term;
    __syncthreads();
    if (t == 0)
        atomicAdd(out, (wsum[0] + wsum[1] + wsum[2] + wsum[3]) *
                       (1.0f / (float)TWO_B));
}

// ---------------------------------------------------------------------------
extern "C" void kernel_launch(void* const* d_in, const int* in_sizes, int n_in,
                              void* d_out, int out_size, void* d_ws, size_t ws_size,
                              hipStream_t stream)
{
    const float* p1 = (const float*)d_in[0];
    const float* p2 = (const float*)d_in[1];
    float* out = (float*)d_out;

    // Workspace layout (all fully rewritten every call; poison-safe):
    //   z4t      : 8192*256 fp4 (fragment-ordered) = 2,097,152 B
    //   pos      : 4096 f32                        =    16,384 B
    //   partial  : 64*8192 f32                     = 2,097,152 B
    char* ws = (char*)d_ws;
    unsigned char* z4  = (unsigned char*)ws;
    float* pos         = (float*)(ws + 2097152);
    float* partial     = (float*)(ws + 2097152 + 16384);

    norm_kernel<<<BATCH, 256, 0, stream>>>(p1, p2, z4, pos, out);
    sim_kernel<<<NTRI, 256, 0, stream>>>(z4, partial);
    lse_kernel<<<32, 256, 0, stream>>>(partial, pos, out);
}